// Round 1
// baseline (111.473 us; speedup 1.0000x reference)
//
#include <hip/hip_runtime.h>
#include <hip/hip_bf16.h>

#define BB 16384
#define LL 256
#define HH 16
#define ROWS_PER_BLOCK 8

__global__ __launch_bounds__(256) void mlp_sigmoid_kernel(
    const float* __restrict__ y,
    const float* __restrict__ W1,
    const float* __restrict__ b1,
    const float* __restrict__ W2,
    const float* __restrict__ b2,
    float* __restrict__ out) {
    const int l = threadIdx.x;          // 0..255 — one latent per thread
    // Hoist per-latent params into registers; reused across ROWS_PER_BLOCK rows.
    float w1[HH], c1[HH], w2[HH];
    #pragma unroll
    for (int h = 0; h < HH; ++h) {
        w1[h] = W1[l * HH + h];
        c1[h] = b1[l * HH + h];
        w2[h] = W2[l * HH + h];
    }
    const float bias2 = b2[l];

    const int b0 = blockIdx.x * ROWS_PER_BLOCK;
    #pragma unroll
    for (int r = 0; r < ROWS_PER_BLOCK; ++r) {
        const int b = b0 + r;
        const float yv = y[b * LL + l];           // coalesced: lane l -> +4B
        float acc = bias2;
        #pragma unroll
        for (int h = 0; h < HH; ++h) {
            float x  = fmaf(yv, w1[h], c1[h]);
            // stable softplus: max(x,0) + log1p(exp(-|x|))
            float ax = fabsf(x);
            float sp = fmaxf(x, 0.0f) + __logf(1.0f + __expf(-ax));
            acc = fmaf(sp, w2[h], acc);
        }
        // sigmoid
        float e = __expf(-acc);
        out[b * LL + l] = __builtin_amdgcn_rcpf(1.0f + e);
    }
}

extern "C" void kernel_launch(void* const* d_in, const int* in_sizes, int n_in,
                              void* d_out, int out_size, void* d_ws, size_t ws_size,
                              hipStream_t stream) {
    // inputs: 0=t (int scalar), 1=y [B,L], 2=W1 [L,H], 3=b1 [L,H], 4=W2 [L,H], 5=b2 [L], 6=args
    const float* y  = (const float*)d_in[1];
    const float* W1 = (const float*)d_in[2];
    const float* b1 = (const float*)d_in[3];
    const float* W2 = (const float*)d_in[4];
    const float* b2 = (const float*)d_in[5];
    float* out = (float*)d_out;

    const int grid = BB / ROWS_PER_BLOCK;   // 2048 blocks x 256 threads
    mlp_sigmoid_kernel<<<grid, 256, 0, stream>>>(y, W1, b1, W2, b2, out);
}

// Round 3
// 98.464 us; speedup vs baseline: 1.1321x; 1.1321x over previous
//
#include <hip/hip_runtime.h>
#include <hip/hip_bf16.h>

#define BB 16384
#define LL 256
#define HH 16
#define ROWS 16   // samples per block; grid = 16384/16 = 1024 blocks = 4/CU

// v_exp_f32 computes 2^x, v_log_f32 computes log2(x)
static __device__ __forceinline__ float fast_exp2(float x) {
#if __has_builtin(__builtin_amdgcn_exp2f)
    return __builtin_amdgcn_exp2f(x);
#else
    return __exp2f(x);
#endif
}
static __device__ __forceinline__ float fast_log2(float x) {
#if __has_builtin(__builtin_amdgcn_logf)
    return __builtin_amdgcn_logf(x);
#else
    return __log2f(x);
#endif
}

__global__ __launch_bounds__(256) void mlp_sigmoid_kernel(
    const float* __restrict__ y,
    const float* __restrict__ W1,
    const float* __restrict__ b1,
    const float* __restrict__ W2,
    const float* __restrict__ b2,
    float* __restrict__ out) {
    const int l = threadIdx.x;              // one latent per thread
    const float LOG2E = 1.4426950408889634f;

    // Vectorized param load: each thread's 16-float row is 64B contiguous.
    float w1[HH], c1[HH], w2[HH];
    {
        const float4* W1v = (const float4*)(W1 + l * HH);
        const float4* b1v = (const float4*)(b1 + l * HH);
        const float4* W2v = (const float4*)(W2 + l * HH);
        #pragma unroll
        for (int i = 0; i < 4; ++i) {
            float4 a = W1v[i], b = b1v[i], c = W2v[i];
            // fold log2e into layer-1 params: x2 = log2e*(y*w1+b1)
            w1[4*i+0] = a.x * LOG2E; w1[4*i+1] = a.y * LOG2E;
            w1[4*i+2] = a.z * LOG2E; w1[4*i+3] = a.w * LOG2E;
            c1[4*i+0] = b.x * LOG2E; c1[4*i+1] = b.y * LOG2E;
            c1[4*i+2] = b.z * LOG2E; c1[4*i+3] = b.w * LOG2E;
            w2[4*i+0] = c.x; w2[4*i+1] = c.y;
            w2[4*i+2] = c.z; w2[4*i+3] = c.w;
        }
    }
    const float bias2 = b2[l] * LOG2E;      // fold log2e into final logit

    const int b0 = blockIdx.x * ROWS;
    #pragma unroll
    for (int r = 0; r < ROWS; ++r) {
        const float yv = y[(b0 + r) * LL + l];     // coalesced
        // acc2 = log2e * logit = sum_h w2[h]*log2(1+2^x2[h]) + b2*log2e
        float acc2 = bias2;
        #pragma unroll
        for (int h = 0; h < HH; ++h) {
            float x2 = fmaf(yv, w1[h], c1[h]);            // x * log2e
            float e  = fast_exp2(-fabsf(x2));             // -|x2| is a free src modifier
            float sp = fmaxf(x2, 0.0f) + fast_log2(1.0f + e); // stable log2(1+2^x2)
            acc2 = fmaf(sp, w2[h], acc2);
        }
        // sigmoid(logit) = 1/(1+2^-acc2)
        float e = fast_exp2(-acc2);
        out[(b0 + r) * LL + l] = __builtin_amdgcn_rcpf(1.0f + e);
    }
}

extern "C" void kernel_launch(void* const* d_in, const int* in_sizes, int n_in,
                              void* d_out, int out_size, void* d_ws, size_t ws_size,
                              hipStream_t stream) {
    // inputs: 0=t, 1=y [B,L], 2=W1 [L,H], 3=b1 [L,H], 4=W2 [L,H], 5=b2 [L], 6=args
    const float* y  = (const float*)d_in[1];
    const float* W1 = (const float*)d_in[2];
    const float* b1 = (const float*)d_in[3];
    const float* W2 = (const float*)d_in[4];
    const float* b2 = (const float*)d_in[5];
    float* out = (float*)d_out;

    mlp_sigmoid_kernel<<<BB / ROWS, 256, 0, stream>>>(y, W1, b1, W2, b2, out);
}

// Round 4
// 95.753 us; speedup vs baseline: 1.1642x; 1.0283x over previous
//
#include <hip/hip_runtime.h>
#include <hip/hip_bf16.h>

#define BB 16384
#define LL 256
#define HH 16
#define ROWS 8   // samples per block; grid = 16384/8 = 2048 blocks (~8/CU of work)

// v_exp_f32 computes 2^x, v_log_f32 computes log2(x)
static __device__ __forceinline__ float fast_exp2(float x) {
#if __has_builtin(__builtin_amdgcn_exp2f)
    return __builtin_amdgcn_exp2f(x);
#else
    return __exp2f(x);
#endif
}
static __device__ __forceinline__ float fast_log2(float x) {
#if __has_builtin(__builtin_amdgcn_logf)
    return __builtin_amdgcn_logf(x);
#else
    return __log2f(x);
#endif
}

__global__ __launch_bounds__(256, 4) void mlp_sigmoid_kernel(
    const float* __restrict__ y,
    const float* __restrict__ W1,
    const float* __restrict__ b1,
    const float* __restrict__ W2,
    const float* __restrict__ b2,
    float* __restrict__ out) {
    const int l = threadIdx.x;              // one latent per thread
    const float LOG2E = 1.4426950408889634f;

    // Vectorized param load: each thread's 16-float row is 64B contiguous.
    float w1[HH], c1[HH], w2[HH];
    {
        const float4* W1v = (const float4*)(W1 + l * HH);
        const float4* b1v = (const float4*)(b1 + l * HH);
        const float4* W2v = (const float4*)(W2 + l * HH);
        #pragma unroll
        for (int i = 0; i < 4; ++i) {
            float4 a = W1v[i], b = b1v[i], c = W2v[i];
            // fold log2e into layer-1 params: x2 = log2e*(y*w1+b1)
            w1[4*i+0] = a.x * LOG2E; w1[4*i+1] = a.y * LOG2E;
            w1[4*i+2] = a.z * LOG2E; w1[4*i+3] = a.w * LOG2E;
            c1[4*i+0] = b.x * LOG2E; c1[4*i+1] = b.y * LOG2E;
            c1[4*i+2] = b.z * LOG2E; c1[4*i+3] = b.w * LOG2E;
            w2[4*i+0] = c.x; w2[4*i+1] = c.y;
            w2[4*i+2] = c.z; w2[4*i+3] = c.w;
        }
    }
    const float bias2 = b2[l] * LOG2E;      // fold log2e into final logit

    const int b0 = blockIdx.x * ROWS;
    // unroll 2 (not full): 2 independent dep-chains of ILP without blowing
    // VGPR pressure across 8 rows x 16 h of live temporaries.
    #pragma unroll 2
    for (int r = 0; r < ROWS; ++r) {
        const float yv = y[(b0 + r) * LL + l];     // coalesced
        // acc2 = log2e * logit = sum_h w2[h]*log2(1+2^x2[h]) + b2*log2e
        float acc2 = bias2;
        #pragma unroll
        for (int h = 0; h < HH; ++h) {
            float x2 = fmaf(yv, w1[h], c1[h]);            // x * log2e
            float e  = fast_exp2(-fabsf(x2));             // -|x2| is a free src modifier
            float sp = fmaxf(x2, 0.0f) + fast_log2(1.0f + e); // stable log2(1+2^x2)
            acc2 = fmaf(sp, w2[h], acc2);
        }
        // sigmoid(logit) = 1/(1+2^-acc2)
        float e = fast_exp2(-acc2);
        out[(b0 + r) * LL + l] = __builtin_amdgcn_rcpf(1.0f + e);
    }
}

extern "C" void kernel_launch(void* const* d_in, const int* in_sizes, int n_in,
                              void* d_out, int out_size, void* d_ws, size_t ws_size,
                              hipStream_t stream) {
    // inputs: 0=t, 1=y [B,L], 2=W1 [L,H], 3=b1 [L,H], 4=W2 [L,H], 5=b2 [L], 6=args
    const float* y  = (const float*)d_in[1];
    const float* W1 = (const float*)d_in[2];
    const float* b1 = (const float*)d_in[3];
    const float* W2 = (const float*)d_in[4];
    const float* b2 = (const float*)d_in[5];
    float* out = (float*)d_out;

    mlp_sigmoid_kernel<<<BB / ROWS, 256, 0, stream>>>(y, W1, b1, W2, b2, out);
}

// Round 5
// 89.429 us; speedup vs baseline: 1.2465x; 1.0707x over previous
//
#include <hip/hip_runtime.h>
#include <hip/hip_bf16.h>

#define BB 16384
#define LL 256
#define HH 16
#define LO (-6.0f)
#define HI (6.0f)
#define NI 256   // intervals
#define NE 257   // entries per latent
#define LT 32    // latents per block tile
#define RP 16    // row-passes per block; samples per block = RP*8 = 128

static __device__ __forceinline__ float fast_exp2(float x) { return __builtin_amdgcn_exp2f(x); }
static __device__ __forceinline__ float fast_log2(float x) { return __builtin_amdgcn_logf(x); }

// Exact per-latent MLP in base-2 domain (verified formulation from R3/R4).
static __device__ __forceinline__ float mlp_exact(
    float yv, int l,
    const float* __restrict__ W1, const float* __restrict__ b1,
    const float* __restrict__ W2, const float* __restrict__ b2) {
    const float LOG2E = 1.4426950408889634f;
    float acc2 = b2[l] * LOG2E;
    #pragma unroll
    for (int h = 0; h < HH; ++h) {
        float x2 = fmaf(yv, W1[l * HH + h] * LOG2E, b1[l * HH + h] * LOG2E);
        float e  = fast_exp2(-fabsf(x2));
        float sp = fmaxf(x2, 0.0f) + fast_log2(1.0f + e);
        acc2 = fmaf(sp, W2[l * HH + h], acc2);
    }
    return __builtin_amdgcn_rcpf(1.0f + fast_exp2(-acc2));
}

// Kernel 1: build LUT tbl[l][i] = sigmoid(f_l(LO + i*(HI-LO)/NI)), i in [0,NE)
__global__ __launch_bounds__(256) void build_lut(
    const float* __restrict__ W1, const float* __restrict__ b1,
    const float* __restrict__ W2, const float* __restrict__ b2,
    float* __restrict__ tbl) {
    int idx = blockIdx.x * 256 + threadIdx.x;   // adjacent lanes share l -> param broadcast
    if (idx >= LL * NE) return;
    int l = idx / NE;
    int i = idx - l * NE;
    float u = LO + (HI - LO) * ((float)i / (float)NI);
    tbl[idx] = mlp_exact(u, l, W1, b1, W2, b2);
}

// Kernel 2: gather + lerp. Block = 256 thr = 32 latents x 8 samples/pass.
__global__ __launch_bounds__(256, 4) void lut_kernel(
    const float* __restrict__ y, float* __restrict__ out,
    const float* __restrict__ tbl,
    const float* __restrict__ W1, const float* __restrict__ b1,
    const float* __restrict__ W2, const float* __restrict__ b2) {
    __shared__ float s[LT * NE];                // 32.9 KB -> 4 blocks/CU
    const int lt = blockIdx.x & 7;              // 8 latent tiles
    const int bb = blockIdx.x >> 3;             // 128 sample blocks
    const int l0 = lt * LT;
    for (int j = threadIdx.x; j < LT * NE; j += 256)
        s[j] = tbl[l0 * NE + j];                // coalesced, L2-resident
    __syncthreads();

    const int l_local = threadIdx.x & (LT - 1);
    const int b_idx   = threadIdx.x >> 5;       // 0..7
    const int l       = l0 + l_local;
    const float* __restrict__ srow = s + l_local * NE;  // bank = (l_local+i)%32
    const float SCALE = (float)NI / (HI - LO);

    int b = bb * (RP * 8) + b_idx;
    #pragma unroll 4
    for (int r = 0; r < RP; ++r, b += 8) {
        float yv = y[b * LL + l];               // 2x128B segments/wave, coalesced
        float t = (yv - LO) * SCALE;
        t = fminf(fmaxf(t, 0.0f), (float)NI);
        int i = (int)t;
        i = min(i, NI - 1);
        float fr = t - (float)i;
        float v0 = srow[i];
        float v1 = srow[i + 1];                 // ds_read2_b32 candidate
        float res = fmaf(fr, v1 - v0, v0);
        if (__builtin_expect(fabsf(yv) > HI, 0)) {
            // exact fallback for out-of-range y (execz-skipped in practice)
            res = mlp_exact(yv, l, W1, b1, W2, b2);
        }
        out[b * LL + l] = res;                  // coalesced
    }
}

extern "C" void kernel_launch(void* const* d_in, const int* in_sizes, int n_in,
                              void* d_out, int out_size, void* d_ws, size_t ws_size,
                              hipStream_t stream) {
    // inputs: 0=t, 1=y [B,L], 2=W1 [L,H], 3=b1 [L,H], 4=W2 [L,H], 5=b2 [L], 6=args
    const float* y  = (const float*)d_in[1];
    const float* W1 = (const float*)d_in[2];
    const float* b1 = (const float*)d_in[3];
    const float* W2 = (const float*)d_in[4];
    const float* b2 = (const float*)d_in[5];
    float* out = (float*)d_out;
    float* tbl = (float*)d_ws;                  // 256*257*4 = 263 KB scratch

    build_lut<<<(LL * NE + 255) / 256, 256, 0, stream>>>(W1, b1, W2, b2, tbl);
    lut_kernel<<<8 * (BB / (RP * 8)), 256, 0, stream>>>(y, out, tbl, W1, b1, W2, b2);
}

// Round 6
// 88.036 us; speedup vs baseline: 1.2662x; 1.0158x over previous
//
#include <hip/hip_runtime.h>
#include <hip/hip_bf16.h>

#define BB 16384
#define LL 256
#define HH 16
#define LO (-6.0f)
#define HI (6.0f)
#define NI 256   // intervals
#define NE 257   // entries per latent
#define LT 32    // latents per block tile
#define RP 16    // row-passes per block; samples per block = RP*8 = 128

static __device__ __forceinline__ float fast_exp2(float x) { return __builtin_amdgcn_exp2f(x); }
static __device__ __forceinline__ float fast_log2(float x) { return __builtin_amdgcn_logf(x); }

// Exact per-latent MLP in base-2 domain (verified R3/R4 formulation).
static __device__ __forceinline__ float mlp_exact(
    float yv, int l,
    const float* __restrict__ W1, const float* __restrict__ b1,
    const float* __restrict__ W2, const float* __restrict__ b2) {
    const float LOG2E = 1.4426950408889634f;
    float acc2 = b2[l] * LOG2E;
    #pragma unroll
    for (int h = 0; h < HH; ++h) {
        float x2 = fmaf(yv, W1[l * HH + h] * LOG2E, b1[l * HH + h] * LOG2E);
        float e  = fast_exp2(-fabsf(x2));
        float sp = fmaxf(x2, 0.0f) + fast_log2(1.0f + e);
        acc2 = fmaf(sp, W2[l * HH + h], acc2);
    }
    return __builtin_amdgcn_rcpf(1.0f + fast_exp2(-acc2));
}

// Kernel 1 v2: 4 lanes per LUT entry (4 h-terms each), shfl butterfly reduce.
// 263168 threads = 4128 waves -> ~4 waves/SIMD (was ~1): hides the trans chain.
__global__ __launch_bounds__(256) void build_lut(
    const float* __restrict__ W1, const float* __restrict__ b1,
    const float* __restrict__ W2, const float* __restrict__ b2,
    float* __restrict__ tbl) {
    const float LOG2E = 1.4426950408889634f;
    int gid = blockIdx.x * 256 + threadIdx.x;
    int entry = gid >> 2;                 // (l, i)
    int q = gid & 3;                      // which h-quad
    if (entry >= LL * NE) return;
    int l = entry / NE;
    int i = entry - l * NE;
    float u = LO + (HI - LO) * ((float)i / (float)NI);

    float part = 0.0f;
    #pragma unroll
    for (int hh = 0; hh < 4; ++hh) {
        int h = q * 4 + hh;
        float x2 = fmaf(u, W1[l * HH + h] * LOG2E, b1[l * HH + h] * LOG2E);
        float e  = fast_exp2(-fabsf(x2));
        float sp = fmaxf(x2, 0.0f) + fast_log2(1.0f + e);
        part = fmaf(sp, W2[l * HH + h], part);
    }
    part += __shfl_xor(part, 1, 64);
    part += __shfl_xor(part, 2, 64);      // lanes q=0..3 all hold full sum
    if (q == 0) {
        float acc2 = part + b2[l] * LOG2E;
        tbl[entry] = __builtin_amdgcn_rcpf(1.0f + fast_exp2(-acc2));
    }
}

// Kernel 2: gather + lerp. Block = 256 thr = 32 latents x 8 samples/pass.
__global__ __launch_bounds__(256, 4) void lut_kernel(
    const float* __restrict__ y, float* __restrict__ out,
    const float* __restrict__ tbl,
    const float* __restrict__ W1, const float* __restrict__ b1,
    const float* __restrict__ W2, const float* __restrict__ b2) {
    __shared__ float s[LT * NE];                // 32.9 KB -> 4 blocks/CU
    const int lt = blockIdx.x & 7;              // 8 latent tiles
    const int bb = blockIdx.x >> 3;             // 128 sample blocks
    const int l0 = lt * LT;
    for (int j = threadIdx.x; j < LT * NE; j += 256)
        s[j] = tbl[l0 * NE + j];                // coalesced, L2-resident
    __syncthreads();

    const int l_local = threadIdx.x & (LT - 1);
    const int b_idx   = threadIdx.x >> 5;       // 0..7
    const int l       = l0 + l_local;
    const float* __restrict__ srow = s + l_local * NE;  // bank = (l_local+i)%32
    const float SCALE = (float)NI / (HI - LO);

    int b = bb * (RP * 8) + b_idx;
    #pragma unroll 4
    for (int r = 0; r < RP; ++r, b += 8) {
        float yv = y[b * LL + l];               // coalesced
        float t = (yv - LO) * SCALE;
        t = fminf(fmaxf(t, 0.0f), (float)NI);
        int i = (int)t;
        i = min(i, NI - 1);
        float fr = t - (float)i;
        float v0 = srow[i];
        float v1 = srow[i + 1];                 // ds_read2_b32 candidate
        float res = fmaf(fr, v1 - v0, v0);
        if (__builtin_expect(fabsf(yv) > HI, 0)) {
            // exact fallback for out-of-range y (execz-skipped in practice)
            res = mlp_exact(yv, l, W1, b1, W2, b2);
        }
        out[b * LL + l] = res;                  // coalesced
    }
}

extern "C" void kernel_launch(void* const* d_in, const int* in_sizes, int n_in,
                              void* d_out, int out_size, void* d_ws, size_t ws_size,
                              hipStream_t stream) {
    // inputs: 0=t, 1=y [B,L], 2=W1 [L,H], 3=b1 [L,H], 4=W2 [L,H], 5=b2 [L], 6=args
    const float* y  = (const float*)d_in[1];
    const float* W1 = (const float*)d_in[2];
    const float* b1 = (const float*)d_in[3];
    const float* W2 = (const float*)d_in[4];
    const float* b2 = (const float*)d_in[5];
    float* out = (float*)d_out;
    float* tbl = (float*)d_ws;                  // 256*257*4 = 263 KB scratch

    build_lut<<<(LL * NE * 4 + 255) / 256, 256, 0, stream>>>(W1, b1, W2, b2, tbl);
    lut_kernel<<<8 * (BB / (RP * 8)), 256, 0, stream>>>(y, out, tbl, W1, b1, W2, b2);
}